// Round 8
// baseline (183.728 us; speedup 1.0000x reference)
//
#include <hip/hip_runtime.h>
#include <cfloat>

#define TOKENS 32768
#define DIM    320
#define NCODE  8192
#define NPAIRW 64                 // pairs of 16-code tiles per wave (wave span = 2048 codes)
#define CERT_UNITS 34             // 34 * 7.63e-6 = 2.6e-4 dot-gap certification

typedef __attribute__((ext_vector_type(8)))  short short8;
typedef __attribute__((ext_vector_type(4)))  float f32x4;
typedef unsigned short ushort_t;
typedef unsigned int   uint_t;

static __device__ __forceinline__ ushort_t f2bf(float f) {
    uint_t u = __float_as_uint(f);
    u += 0x7fffu + ((u >> 16) & 1u);
    return (ushort_t)(u >> 16);
}
static __device__ __forceinline__ float bf2f(ushort_t h) {
    return __uint_as_float(((uint_t)h) << 16);
}
static __device__ __forceinline__ uint_t pack2(ushort_t a, ushort_t b) {
    return (uint_t)a | ((uint_t)b << 16);
}
static __device__ __forceinline__ int imaxi(int a, int b) { return a > b ? a : b; }
static __device__ __forceinline__ int imini(int a, int b) { return a < b ? a : b; }
static __device__ __forceinline__ int med3i(int a, int b, int c) {
    int d; asm("v_med3_i32 %0, %1, %2, %3" : "=v"(d) : "v"(a), "v"(b), "v"(c)); return d;
}
static __device__ __forceinline__ int max3i(int a, int b, int c) {
    int d; asm("v_max3_i32 %0, %1, %2, %3" : "=v"(d) : "v"(a), "v"(b), "v"(c)); return d;
}

// ---------------------------------------------------------------------------
// k0: codebook c2 + bf16 hi/lo pack in 16x16x32 B-FRAGMENT layout (R6 layout):
// per 16-code tile, 64 lane-slots of 16 B; slot (g*16+n): n=code&15, g=k-group:
//   g=0: hi[0..8)  g=1: hi[8..16)  g=2: lo[0..8)  g=3: lo[8..16)
// ---------------------------------------------------------------------------
__global__ __launch_bounds__(256) void pack_kernel(
    const float* __restrict__ cb,    // (8192, 16)
    float* __restrict__ c2o,         // (8192)
    ushort_t* __restrict__ cbpack)   // (512 tiles, 512 ushorts)
{
    int j = blockIdx.x * 256 + threadIdx.x;
    const float4* cr4 = (const float4*)(cb + (size_t)j * 16);
    float4 c0 = cr4[0], c1 = cr4[1], c2v = cr4[2], c3 = cr4[3];
    float c[16] = {c0.x, c0.y, c0.z, c0.w, c1.x, c1.y, c1.z, c1.w,
                   c2v.x, c2v.y, c2v.z, c2v.w, c3.x, c3.y, c3.z, c3.w};
    float s = 0.f;
    #pragma unroll
    for (int k = 0; k < 16; ++k) s = fmaf(c[k], c[k], s);
    c2o[j] = s;
    ushort_t hi[16], lo[16];
    #pragma unroll
    for (int k = 0; k < 16; ++k) {
        hi[k] = f2bf(c[k]);
        lo[k] = f2bf(c[k] - bf2f(hi[k]));
    }
    size_t base = (size_t)(j >> 4) * 512;   // tile base, ushorts
    int n = j & 15;
    *(uint4*)(cbpack + base + (size_t)(0 * 16 + n) * 8) =
        make_uint4(pack2(hi[0], hi[1]), pack2(hi[2], hi[3]),
                   pack2(hi[4], hi[5]), pack2(hi[6], hi[7]));
    *(uint4*)(cbpack + base + (size_t)(1 * 16 + n) * 8) =
        make_uint4(pack2(hi[8], hi[9]), pack2(hi[10], hi[11]),
                   pack2(hi[12], hi[13]), pack2(hi[14], hi[15]));
    *(uint4*)(cbpack + base + (size_t)(2 * 16 + n) * 8) =
        make_uint4(pack2(lo[0], lo[1]), pack2(lo[2], lo[3]),
                   pack2(lo[4], lo[5]), pack2(lo[6], lo[7]));
    *(uint4*)(cbpack + base + (size_t)(3 * 16 + n) * 8) =
        make_uint4(pack2(lo[8], lo[9]), pack2(lo[10], lo[11]),
                   pack2(lo[12], lo[13]), pack2(lo[14], lo[15]));
}

// ---------------------------------------------------------------------------
// k1: projection only (R6 Phase A math verbatim, P read straight from L2 —
// no LDS, no barriers). 16 lanes/token, 16 tokens/block. Writes:
//   Apack (32768 x 32 ushorts: hi[16]|lo[16], 2^17-prescaled)
//   tn    (32768 x 16 f32, UNSCALED, for exact fallback)
//   x2    (32768 f32)
// ---------------------------------------------------------------------------
__global__ __launch_bounds__(256) void project_kernel(
    const float* __restrict__ x,        // (32768, 320)
    const float* __restrict__ P,        // (320, 16)
    ushort_t* __restrict__ Apack,
    float* __restrict__ tn,
    float* __restrict__ x2)
{
    int tid = threadIdx.x;
    int sub = tid & 15;
    int tk  = tid >> 4;                  // local token 0..15
    int tok = blockIdx.x * 16 + tk;

    const float* xr = x + (size_t)tok * DIM;
    float acc[16];
    #pragma unroll
    for (int k = 0; k < 16; ++k) acc[k] = 0.f;
    for (int i = 0; i < 20; ++i) {
        int d = i * 16 + sub;
        float xv = xr[d];
        const float4* pr = (const float4*)(P + d * 16);
        float4 p0 = pr[0], p1 = pr[1], p2 = pr[2], p3 = pr[3];
        acc[0] = fmaf(xv, p0.x, acc[0]);   acc[1] = fmaf(xv, p0.y, acc[1]);
        acc[2] = fmaf(xv, p0.z, acc[2]);   acc[3] = fmaf(xv, p0.w, acc[3]);
        acc[4] = fmaf(xv, p1.x, acc[4]);   acc[5] = fmaf(xv, p1.y, acc[5]);
        acc[6] = fmaf(xv, p1.z, acc[6]);   acc[7] = fmaf(xv, p1.w, acc[7]);
        acc[8] = fmaf(xv, p2.x, acc[8]);   acc[9] = fmaf(xv, p2.y, acc[9]);
        acc[10] = fmaf(xv, p2.z, acc[10]); acc[11] = fmaf(xv, p2.w, acc[11]);
        acc[12] = fmaf(xv, p3.x, acc[12]); acc[13] = fmaf(xv, p3.y, acc[13]);
        acc[14] = fmaf(xv, p3.z, acc[14]); acc[15] = fmaf(xv, p3.w, acc[15]);
    }
    #pragma unroll
    for (int m = 1; m <= 8; m <<= 1) {
        #pragma unroll
        for (int k = 0; k < 16; ++k)
            acc[k] += __shfl_xor(acc[k], m);
    }
    float ss = 0.f;
    #pragma unroll
    for (int k = 0; k < 16; ++k) ss = fmaf(acc[k], acc[k], ss);
    float nrm = fmaxf(sqrtf(ss), 1e-12f);
    float inv = 1.0f / nrm;
    float t[16];
    #pragma unroll
    for (int k = 0; k < 16; ++k) t[k] = acc[k] * inv;
    float xx = 0.f;
    #pragma unroll
    for (int k = 0; k < 16; ++k) xx = fmaf(t[k], t[k], xx);

    // pre-scale by 2^17 (exact) so MFMA output is already in key units
    ushort_t hi[16], lo[16];
    #pragma unroll
    for (int k = 0; k < 16; ++k) {
        float th = t[k] * 131072.0f;
        hi[k] = f2bf(th);
        lo[k] = f2bf(th - bf2f(hi[k]));
    }
    if (sub < 4) {
        *(float4*)(tn + (size_t)tok * 16 + sub * 4) =
            make_float4(t[4 * sub], t[4 * sub + 1], t[4 * sub + 2], t[4 * sub + 3]);
    }
    uint4* dst = (uint4*)(Apack + (size_t)tok * 32);
    if (sub == 4) dst[0] = make_uint4(pack2(hi[0], hi[1]), pack2(hi[2], hi[3]),
                                      pack2(hi[4], hi[5]), pack2(hi[6], hi[7]));
    if (sub == 5) dst[1] = make_uint4(pack2(hi[8], hi[9]), pack2(hi[10], hi[11]),
                                      pack2(hi[12], hi[13]), pack2(hi[14], hi[15]));
    if (sub == 6) dst[2] = make_uint4(pack2(lo[0], lo[1]), pack2(lo[2], lo[3]),
                                      pack2(lo[4], lo[5]), pack2(lo[6], lo[7]));
    if (sub == 7) dst[3] = make_uint4(pack2(lo[8], lo[9]), pack2(lo[10], lo[11]),
                                      pack2(lo[12], lo[13]), pack2(lo[14], lo[15]));
    if (sub == 8) x2[tok] = xx;
}

// ---------------------------------------------------------------------------
// k2: search + merge + cert + exact fallback (R6 Phase B/C/D verbatim,
// decoupled). 16 tokens/block, 4 waves, each wave scans 2048 codes with the
// distance-2 L/M/E pipeline. No big LDS (~1.3 KB) -> occupancy bound only by
// VGPR; 2048 independent blocks. A-fragments read from global Apack.
// ---------------------------------------------------------------------------
__global__ __launch_bounds__(256, 4) void search_kernel(
    const ushort_t* __restrict__ Apack,
    const ushort_t* __restrict__ cbpack,
    const float* __restrict__ cb,       // (8192, 16) fp32
    const float* __restrict__ c2g,      // (8192)
    const float* __restrict__ tn,       // (32768, 16)
    const float* __restrict__ x2g,      // (32768)
    int* __restrict__ out)
{
    __shared__ int mergeS[4][16][2];
    __shared__ int flagS[20];            // [0..15] list, [16] count
    __shared__ float redE[4];
    __shared__ int   redI[4];

    int tid  = threadIdx.x;
    int lane = tid & 63;
    int wave = tid >> 6;                 // 0..3
    int n    = lane & 15;                // code column within tile
    int g    = lane >> 4;                // k-group 0..3
    if (tid == 0) flagS[16] = 0;

    int tokbase = blockIdx.x * 16;
    {
        const ushort_t* ar = Apack + (size_t)(tokbase + n) * 32;
        short8 a1 = *(const short8*)(ar + (g & 1) * 8);        // hiA slices
        short8 a2 = *(const short8*)(ar + 16 + (g & 1) * 8);   // loA slices

        f32x4 zero = {};
        int p1[4], p2[4];
        #pragma unroll
        for (int r = 0; r < 4; ++r) { p1[r] = (int)0x80000000; p2[r] = (int)0x80000000; }

        int wavebase = wave * 2048;
        const ushort_t* cpb = cbpack + (size_t)(wavebase >> 4) * 512 + (size_t)lane * 8;

#define LOADP(PIDX, BA, BB) do {                                           \
            const ushort_t* cp_ = cpb + (size_t)(PIDX) * 1024;             \
            (BA) = *(const short8*)(cp_);                                  \
            (BB) = *(const short8*)(cp_ + 512);                            \
        } while (0)

#define MFMAP(BA, BB, AA, AB) do {                                                    \
            (AA) = __builtin_amdgcn_mfma_f32_16x16x32_bf16(a1, (BA), zero, 0, 0, 0);  \
            (AA) = __builtin_amdgcn_mfma_f32_16x16x32_bf16(a2, (BA), (AA), 0, 0, 0);  \
            (AB) = __builtin_amdgcn_mfma_f32_16x16x32_bf16(a1, (BB), zero, 0, 0, 0);  \
            (AB) = __builtin_amdgcn_mfma_f32_16x16x32_bf16(a2, (BB), (AB), 0, 0, 0);  \
        } while (0)

#define EPIP(AA, AB, INV) do {                                             \
            _Pragma("unroll")                                              \
            for (int r = 0; r < 4; ++r) {                                  \
                int ka = (int)(AA)[r];                                     \
                int kb = (int)(AB)[r];                                     \
                int pa = (int)(((uint_t)ka << 13) | (uint_t)(INV));        \
                int pb = (int)(((uint_t)kb << 13) | (uint_t)((INV) - 16)); \
                int m3 = med3i(p1[r], pa, pb);                             \
                p1[r] = max3i(p1[r], pa, pb);                              \
                p2[r] = imaxi(p2[r], m3);                                  \
            }                                                              \
        } while (0)

        short8 Xa, Xb;                 // buffer X (pair: 2 tile B-frags)
        short8 Ya, Yb;                 // buffer Y
        f32x4 aA0, aB0, aA1, aB1;      // two acc pair-sets

        // prologue: load pairs 0,1; MFMA pair 0
        LOADP(0, Xa, Xb);
        LOADP(1, Ya, Yb);
        MFMAP(Xa, Xb, aA0, aB0);                        // M(0)
        int invA = 8191 - wavebase - n;                 // pair 0, tile A

        // steady state: 31 iterations, 2 pairs each
        #pragma unroll 1
        for (int k = 1; k < NPAIRW - 1; k += 2) {
            LOADP(k + 1, Xa, Xb);                       // L(k+1) -> X
            MFMAP(Ya, Yb, aA1, aB1);                    // M(k)   from Y
            EPIP(aA0, aB0, invA);  invA -= 32;          // E(k-1)
            LOADP(k + 2, Ya, Yb);                       // L(k+2) -> Y
            MFMAP(Xa, Xb, aA0, aB0);                    // M(k+1) from X
            EPIP(aA1, aB1, invA);  invA -= 32;          // E(k)
        }
        // tail: M(63) from Y, then drain E(62), E(63)
        MFMAP(Ya, Yb, aA1, aB1);                        // M(NPAIRW-1)
        EPIP(aA0, aB0, invA);  invA -= 32;              // E(NPAIRW-2)
        EPIP(aA1, aB1, invA);                           // E(NPAIRW-1)

#undef LOADP
#undef MFMAP
#undef EPIP

        // cross-lane top-2 merge within 16-lane groups (16 code columns)
        #pragma unroll
        for (int mask = 1; mask <= 8; mask <<= 1) {
            #pragma unroll
            for (int r = 0; r < 4; ++r) {
                int q1 = __shfl_xor(p1[r], mask);
                int q2 = __shfl_xor(p2[r], mask);
                int np2 = imaxi(imini(p1[r], q1), imaxi(p2[r], q2));
                p1[r] = imaxi(p1[r], q1);
                p2[r] = np2;
            }
        }
        // lane n==r of each group writes token row g*4+r (local 0..15)
        #pragma unroll
        for (int r = 0; r < 4; ++r) {
            if (n == r) {
                mergeS[wave][g * 4 + r][0] = p1[r];
                mergeS[wave][g * 4 + r][1] = p2[r];
            }
        }
    }
    __syncthreads();

    // ---- merge 4 waves, decode, certify (signed keys) ----
    if (tid < 16) {
        int p1 = mergeS[0][tid][0], p2 = mergeS[0][tid][1];
        #pragma unroll
        for (int w = 1; w < 4; ++w) {
            int q1 = mergeS[w][tid][0];
            int q2 = mergeS[w][tid][1];
            int np2 = imaxi(imini(p1, q1), imaxi(p2, q2));
            p1 = imaxi(p1, q1);
            p2 = np2;
        }
        if (((p1 >> 13) - (p2 >> 13)) <= CERT_UNITS) {
            int pz = atomicAdd(&flagS[16], 1);
            flagS[pz] = tid;
        } else {
            out[tokbase + tid] = 8191 - (p1 & 8191);
        }
    }
    __syncthreads();

    // ---- exact fp32 rescan of flagged tokens (rare) ----
    // R1-validated rounding: ascending fmaf dot, fmaf(-2,dot,x2+c2),
    // lexicographic (e, j) min == first-occurrence argmin.
    int nf = flagS[16];
    for (int fi = 0; fi < nf; ++fi) {
        int ftk = flagS[fi];
        float a[16];
        #pragma unroll
        for (int k = 0; k < 16; ++k) a[k] = tn[(size_t)(tokbase + ftk) * 16 + k];
        float xx = x2g[tokbase + ftk];
        float mn = FLT_MAX;
        int   id = 0x7fffffff;
        for (int c = 0; c < 32; ++c) {
            int j = c * 256 + tid;
            const float4* c4 = (const float4*)(cb + (size_t)j * 16);
            float4 c0 = c4[0], c1 = c4[1], c2v = c4[2], c3 = c4[3];
            float dot = 0.f;
            dot = fmaf(a[0], c0.x, dot);   dot = fmaf(a[1], c0.y, dot);
            dot = fmaf(a[2], c0.z, dot);   dot = fmaf(a[3], c0.w, dot);
            dot = fmaf(a[4], c1.x, dot);   dot = fmaf(a[5], c1.y, dot);
            dot = fmaf(a[6], c1.z, dot);   dot = fmaf(a[7], c1.w, dot);
            dot = fmaf(a[8], c2v.x, dot);  dot = fmaf(a[9], c2v.y, dot);
            dot = fmaf(a[10], c2v.z, dot); dot = fmaf(a[11], c2v.w, dot);
            dot = fmaf(a[12], c3.x, dot);  dot = fmaf(a[13], c3.y, dot);
            dot = fmaf(a[14], c3.z, dot);  dot = fmaf(a[15], c3.w, dot);
            float e = fmaf(-2.f, dot, xx + c2g[j]);
            if (e < mn || (e == mn && j < id)) { mn = e; id = j; }
        }
        #pragma unroll
        for (int mask = 1; mask <= 32; mask <<= 1) {
            float pmn = __shfl_xor(mn, mask);
            int   pid = __shfl_xor(id, mask);
            if (pmn < mn || (pmn == mn && pid < id)) { mn = pmn; id = pid; }
        }
        if (lane == 0) { redE[wave] = mn; redI[wave] = id; }
        __syncthreads();
        if (tid == 0) {
            #pragma unroll
            for (int w = 1; w < 4; ++w) {
                float pe = redE[w]; int pi = redI[w];
                if (pe < mn || (pe == mn && pi < id)) { mn = pe; id = pi; }
            }
            out[tokbase + ftk] = id;
        }
        __syncthreads();
    }
}

extern "C" void kernel_launch(void* const* d_in, const int* in_sizes, int n_in,
                              void* d_out, int out_size, void* d_ws, size_t ws_size,
                              hipStream_t stream) {
    const float* x   = (const float*)d_in[0];
    const float* P   = (const float*)d_in[1];
    const float* cbn = (const float*)d_in[2];

    // workspace layout (~4.7 MB)
    float*    c2     = (float*)d_ws;                          // 8192 f
    ushort_t* cbpack = (ushort_t*)(c2 + NCODE);               // 8192*32 ush (512 KB)
    ushort_t* Apack  = cbpack + (size_t)NCODE * 32;           // 32768*32 ush (2 MB)
    float*    tn     = (float*)(Apack + (size_t)TOKENS * 32); // 32768*16 f (2 MB)
    float*    x2     = tn + (size_t)TOKENS * 16;              // 32768 f (128 KB)
    int* labels = (int*)d_out;

    pack_kernel<<<NCODE / 256, 256, 0, stream>>>(cbn, c2, cbpack);
    project_kernel<<<TOKENS / 16, 256, 0, stream>>>(x, P, Apack, tn, x2);
    search_kernel<<<TOKENS / 16, 256, 0, stream>>>(Apack, cbpack, cbn, c2, tn, x2, labels);
}

// Round 9
// 159.004 us; speedup vs baseline: 1.1555x; 1.1555x over previous
//
#include <hip/hip_runtime.h>
#include <cfloat>

#define TOKENS 32768
#define DIM    320
#define NCODE  8192
#define PROW   20                 // P row pitch in LDS floats (stride-8 conflict-free)
#define APAD   40                 // ApackS row pitch in ushorts (80 B -> 8 bank-starts)
#define NPAIR  32                 // pairs of 32-code tiles per wave (wave span = 2048)
#define CERT_UNITS 34             // 34 * 7.63e-6 = 2.6e-4 dot-gap certification

typedef __attribute__((ext_vector_type(8)))  short short8;
typedef __attribute__((ext_vector_type(16))) float f32x16;
typedef unsigned short ushort_t;
typedef unsigned int   uint_t;

static __device__ __forceinline__ ushort_t f2bf(float f) {
    uint_t u = __float_as_uint(f);
    u += 0x7fffu + ((u >> 16) & 1u);
    return (ushort_t)(u >> 16);
}
static __device__ __forceinline__ float bf2f(ushort_t h) {
    return __uint_as_float(((uint_t)h) << 16);
}
static __device__ __forceinline__ uint_t pack2(ushort_t a, ushort_t b) {
    return (uint_t)a | ((uint_t)b << 16);
}
static __device__ __forceinline__ int imaxi(int a, int b) { return a > b ? a : b; }
static __device__ __forceinline__ int imini(int a, int b) { return a < b ? a : b; }
// exact top-2 merge helpers: second-best of {p1,pa,pb} is the median
static __device__ __forceinline__ int med3i(int a, int b, int c) {
    int d; asm("v_med3_i32 %0, %1, %2, %3" : "=v"(d) : "v"(a), "v"(b), "v"(c)); return d;
}
static __device__ __forceinline__ int max3i(int a, int b, int c) {
    int d; asm("v_max3_i32 %0, %1, %2, %3" : "=v"(d) : "v"(a), "v"(b), "v"(c)); return d;
}

// ---------------------------------------------------------------------------
// k0: codebook c2 (ascending-k fmaf, matches fallback math) + bf16 hi/lo pack.
// Codebook side stays UNSCALED; the 2^17 key scale lives on the token side.
// ---------------------------------------------------------------------------
__global__ __launch_bounds__(256) void pack_kernel(
    const float* __restrict__ cb,    // (8192, 16)
    float* __restrict__ c2o,         // (8192)
    ushort_t* __restrict__ cbpack)   // (8192, 32) [hi16|lo16]
{
    int j = blockIdx.x * 256 + threadIdx.x;
    const float4* cr4 = (const float4*)(cb + (size_t)j * 16);
    float4 c0 = cr4[0], c1 = cr4[1], c2v = cr4[2], c3 = cr4[3];
    float c[16] = {c0.x, c0.y, c0.z, c0.w, c1.x, c1.y, c1.z, c1.w,
                   c2v.x, c2v.y, c2v.z, c2v.w, c3.x, c3.y, c3.z, c3.w};
    float s = 0.f;
    #pragma unroll
    for (int k = 0; k < 16; ++k) s = fmaf(c[k], c[k], s);
    c2o[j] = s;
    ushort_t hi[16], lo[16];
    #pragma unroll
    for (int k = 0; k < 16; ++k) {
        hi[k] = f2bf(c[k]);
        lo[k] = f2bf(c[k] - bf2f(hi[k]));
    }
    uint4* dst = (uint4*)(cbpack + (size_t)j * 32);
    dst[0] = make_uint4(pack2(hi[0], hi[1]), pack2(hi[2], hi[3]),
                        pack2(hi[4], hi[5]), pack2(hi[6], hi[7]));
    dst[1] = make_uint4(pack2(hi[8], hi[9]), pack2(hi[10], hi[11]),
                        pack2(hi[12], hi[13]), pack2(hi[14], hi[15]));
    dst[2] = make_uint4(pack2(lo[0], lo[1]), pack2(lo[2], lo[3]),
                        pack2(lo[4], lo[5]), pack2(lo[6], lo[7]));
    dst[3] = make_uint4(pack2(lo[8], lo[9]), pack2(lo[10], lo[11]),
                        pack2(lo[12], lo[13]), pack2(lo[14], lo[15]));
}

// ---------------------------------------------------------------------------
// k1: fused projection + search + merge + cert + exact fallback.
// R9 = R2 (best measured: 94.9 us fused) + two surgical overlap levers:
//   * s_setprio(1) around each 6-MFMA cluster — 4-wave blocks with no
//     intra-loop barriers are phase-diverse, the regime where setprio
//     measurably helps (learn_hip m191).
//   * sched_barrier(0) after each LOADP — stops the compiler sinking the
//     B-loads toward their uses, preserving the designed full-iteration
//     load->use slack.
// Everything else byte-identical to R2.
// ---------------------------------------------------------------------------
__global__ __launch_bounds__(256, 2) void fused_kernel(
    const float* __restrict__ x,        // (32768, 320)
    const float* __restrict__ P,        // (320, 16)
    const float* __restrict__ cb,       // (8192, 16) fp32
    const float* __restrict__ c2g,      // (8192)
    const ushort_t* __restrict__ cbpack,// (8192, 32)
    int* __restrict__ out)
{
    __shared__ float Ps[DIM * PROW];         // 25.6 KB
    __shared__ ushort_t ApackS[32 * APAD];   // 2.5 KB padded rows
    __shared__ float tnS[32 * 16];           // 2 KB fp32 for fallback (UNSCALED)
    __shared__ float x2S[32];
    __shared__ int mergeS[4][32][2];         // 1 KB (signed keys)
    __shared__ int flagS[36];                // [0..31] list, [32] count
    __shared__ float redE[4];
    __shared__ int   redI[4];

    int tid = threadIdx.x;
    if (tid == 0) flagS[32] = 0;

    // ---- Phase A: stage P, project 32 tokens (8 lanes/token) ----
    {
        const float4* P4 = (const float4*)P;
        #pragma unroll
        for (int i = 0; i < 5; ++i) {
            int idx = tid + i * 256;
            int row = idx >> 2, col = idx & 3;
            *(float4*)(Ps + row * PROW + col * 4) = P4[idx];
        }
    }
    __syncthreads();

    int sub = tid & 7;
    int tk  = tid >> 3;                  // local token 0..31
    int tok = blockIdx.x * 32 + tk;
    {
        const float* xr = x + (size_t)tok * DIM;
        float acc[16];
        #pragma unroll
        for (int k = 0; k < 16; ++k) acc[k] = 0.f;
        for (int i = 0; i < 40; ++i) {
            int d = i * 8 + sub;
            float xv = xr[d];
            const float4* pr = (const float4*)(Ps + d * PROW);
            float4 p0 = pr[0], p1 = pr[1], p2 = pr[2], p3 = pr[3];
            acc[0] = fmaf(xv, p0.x, acc[0]);   acc[1] = fmaf(xv, p0.y, acc[1]);
            acc[2] = fmaf(xv, p0.z, acc[2]);   acc[3] = fmaf(xv, p0.w, acc[3]);
            acc[4] = fmaf(xv, p1.x, acc[4]);   acc[5] = fmaf(xv, p1.y, acc[5]);
            acc[6] = fmaf(xv, p1.z, acc[6]);   acc[7] = fmaf(xv, p1.w, acc[7]);
            acc[8] = fmaf(xv, p2.x, acc[8]);   acc[9] = fmaf(xv, p2.y, acc[9]);
            acc[10] = fmaf(xv, p2.z, acc[10]); acc[11] = fmaf(xv, p2.w, acc[11]);
            acc[12] = fmaf(xv, p3.x, acc[12]); acc[13] = fmaf(xv, p3.y, acc[13]);
            acc[14] = fmaf(xv, p3.z, acc[14]); acc[15] = fmaf(xv, p3.w, acc[15]);
        }
        #pragma unroll
        for (int m = 1; m <= 4; m <<= 1) {
            #pragma unroll
            for (int k = 0; k < 16; ++k)
                acc[k] += __shfl_xor(acc[k], m);
        }
        float ss = 0.f;
        #pragma unroll
        for (int k = 0; k < 16; ++k) ss = fmaf(acc[k], acc[k], ss);
        float nrm = fmaxf(sqrtf(ss), 1e-12f);
        float inv = 1.0f / nrm;
        float t[16];
        #pragma unroll
        for (int k = 0; k < 16; ++k) t[k] = acc[k] * inv;
        float xx = 0.f;
        #pragma unroll
        for (int k = 0; k < 16; ++k) xx = fmaf(t[k], t[k], xx);

        // pre-scale by 2^17 (exact) so MFMA output is already in key units
        ushort_t hi[16], lo[16];
        #pragma unroll
        for (int k = 0; k < 16; ++k) {
            float th = t[k] * 131072.0f;
            hi[k] = f2bf(th);
            lo[k] = f2bf(th - bf2f(hi[k]));
        }
        if (sub < 4) {
            *(float4*)(tnS + tk * 16 + sub * 4) =
                make_float4(t[4 * sub], t[4 * sub + 1], t[4 * sub + 2], t[4 * sub + 3]);
        }
        uint4* dst = (uint4*)(ApackS + tk * APAD);   // 80 B rows, 16-B aligned
        if (sub == 4) dst[0] = make_uint4(pack2(hi[0], hi[1]), pack2(hi[2], hi[3]),
                                          pack2(hi[4], hi[5]), pack2(hi[6], hi[7]));
        if (sub == 5) dst[1] = make_uint4(pack2(hi[8], hi[9]), pack2(hi[10], hi[11]),
                                          pack2(hi[12], hi[13]), pack2(hi[14], hi[15]));
        if (sub == 6) dst[2] = make_uint4(pack2(lo[0], lo[1]), pack2(lo[2], lo[3]),
                                          pack2(lo[4], lo[5]), pack2(lo[6], lo[7]));
        if (sub == 7) dst[3] = make_uint4(pack2(lo[8], lo[9]), pack2(lo[10], lo[11]),
                                          pack2(lo[12], lo[13]), pack2(lo[14], lo[15]));
        if (sub == 0) x2S[tk] = xx;
    }
    __syncthreads();

    // ---- Phase B: distance-2 pipelined pair-tile search (2048 codes/wave) ----
    int lane = tid & 63;
    int wave = tid >> 6;
    int half = lane >> 5;
    int l31  = lane & 31;
    {
        short8 hiA = *(const short8*)(ApackS + l31 * APAD + half * 8);
        short8 loA = *(const short8*)(ApackS + l31 * APAD + 16 + half * 8);

        f32x16 zero = {};
        int p1[16], p2[16];
        #pragma unroll
        for (int r = 0; r < 16; ++r) { p1[r] = (int)0x80000000; p2[r] = (int)0x80000000; }

        int base = wave * (NPAIR * 64) + l31;
        const ushort_t* cpb = cbpack + (size_t)base * 32;

#define LOADP(PIDX, H0, L0, H1, L1) do {                                   \
            const ushort_t* cp_ = cpb + (size_t)(PIDX) * 2048;             \
            (H0) = *(const short8*)(cp_ + half * 8);                       \
            (L0) = *(const short8*)(cp_ + 16 + half * 8);                  \
            (H1) = *(const short8*)(cp_ + 1024 + half * 8);                \
            (L1) = *(const short8*)(cp_ + 1024 + 16 + half * 8);           \
            __builtin_amdgcn_sched_barrier(0);                             \
        } while (0)

#define MFMAP(H0, L0, H1, L1, AA, AB) do {                                           \
            __builtin_amdgcn_s_setprio(1);                                            \
            (AA) = __builtin_amdgcn_mfma_f32_32x32x16_bf16(hiA, (H0), zero, 0, 0, 0); \
            (AA) = __builtin_amdgcn_mfma_f32_32x32x16_bf16(loA, (H0), (AA), 0, 0, 0); \
            (AA) = __builtin_amdgcn_mfma_f32_32x32x16_bf16(hiA, (L0), (AA), 0, 0, 0); \
            (AB) = __builtin_amdgcn_mfma_f32_32x32x16_bf16(hiA, (H1), zero, 0, 0, 0); \
            (AB) = __builtin_amdgcn_mfma_f32_32x32x16_bf16(loA, (H1), (AB), 0, 0, 0); \
            (AB) = __builtin_amdgcn_mfma_f32_32x32x16_bf16(hiA, (L1), (AB), 0, 0, 0); \
            __builtin_amdgcn_s_setprio(0);                                            \
        } while (0)

#define EPIP(AA, AB, INVA) do {                                            \
            int invB_ = (INVA) - 32;                                       \
            _Pragma("unroll")                                              \
            for (int r = 0; r < 16; ++r) {                                 \
                int ka = (int)(AA)[r];                                     \
                int kb = (int)(AB)[r];                                     \
                int pa = (int)(((uint_t)ka << 13) | (uint_t)(INVA));       \
                int pb = (int)(((uint_t)kb << 13) | (uint_t)invB_);        \
                int m3 = med3i(p1[r], pa, pb);                             \
                p1[r] = max3i(p1[r], pa, pb);                              \
                p2[r] = imaxi(p2[r], m3);                                  \
            }                                                              \
        } while (0)

        short8 Xh0, Xl0, Xh1, Xl1;     // buffer X
        short8 Yh0, Yl0, Yh1, Yl1;     // buffer Y
        f32x16 aA0, aB0, aA1, aB1;     // two acc pair-sets

        // prologue: load pairs 0,1; MFMA pair 0
        LOADP(0, Xh0, Xl0, Xh1, Xl1);
        LOADP(1, Yh0, Yl0, Yh1, Yl1);
        MFMAP(Xh0, Xl0, Xh1, Xl1, aA0, aB0);          // M(0)
        int inv = 8191 - base;                         // invA of pair 0

        // steady state: 15 iterations, 2 pairs each
        #pragma unroll 1
        for (int k = 1; k < 31; k += 2) {
            LOADP(k + 1, Xh0, Xl0, Xh1, Xl1);          // L(k+1) -> X
            MFMAP(Yh0, Yl0, Yh1, Yl1, aA1, aB1);       // M(k)   from Y
            EPIP(aA0, aB0, inv);  inv -= 64;           // E(k-1)
            LOADP(k + 2, Yh0, Yl0, Yh1, Yl1);          // L(k+2) -> Y
            MFMAP(Xh0, Xl0, Xh1, Xl1, aA0, aB0);       // M(k+1) from X
            EPIP(aA1, aB1, inv);  inv -= 64;           // E(k)
        }
        // tail: M(31) from Y (holds pair 31), then drain E(30), E(31)
        MFMAP(Yh0, Yl0, Yh1, Yl1, aA1, aB1);           // M(31)
        EPIP(aA0, aB0, inv);  inv -= 64;               // E(30)
        EPIP(aA1, aB1, inv);                           // E(31)

#undef LOADP
#undef MFMAP
#undef EPIP

        #pragma unroll
        for (int mask = 1; mask <= 16; mask <<= 1) {
            #pragma unroll
            for (int r = 0; r < 16; ++r) {
                int a1 = __shfl_xor(p1[r], mask);
                int a2 = __shfl_xor(p2[r], mask);
                int np2 = imaxi(imini(p1[r], a1), imaxi(p2[r], a2));
                p1[r] = imaxi(p1[r], a1);
                p2[r] = np2;
            }
        }
        #pragma unroll
        for (int r = 0; r < 16; ++r) {
            if (l31 == r) {
                int mrow = (r & 3) + 8 * (r >> 2) + 4 * half;
                mergeS[wave][mrow][0] = p1[r];
                mergeS[wave][mrow][1] = p2[r];
            }
        }
    }
    __syncthreads();

    // ---- Phase C: merge 4 waves, decode, certify (signed keys) ----
    if (tid < 32) {
        int p1 = mergeS[0][tid][0], p2 = mergeS[0][tid][1];
        #pragma unroll
        for (int w = 1; w < 4; ++w) {
            int a1 = mergeS[w][tid][0];
            int a2 = mergeS[w][tid][1];
            int np2 = imaxi(imini(p1, a1), imaxi(p2, a2));
            p1 = imaxi(p1, a1);
            p2 = np2;
        }
        if (((p1 >> 13) - (p2 >> 13)) <= CERT_UNITS) {
            int pz = atomicAdd(&flagS[32], 1);
            flagS[pz] = tid;
        } else {
            out[blockIdx.x * 32 + tid] = 8191 - (p1 & 8191);
        }
    }
    __syncthreads();

    // ---- Phase D: exact fp32 rescan of flagged tokens (rare) ----
    // R1-validated rounding: ascending fmaf dot, fmaf(-2,dot,x2+c2),
    // lexicographic (e, j) min == first-occurrence argmin.
    int nf = flagS[32];
    for (int fi = 0; fi < nf; ++fi) {
        int ftk = flagS[fi];
        float a[16];
        #pragma unroll
        for (int k = 0; k < 16; ++k) a[k] = tnS[ftk * 16 + k];
        float xx = x2S[ftk];
        float mn = FLT_MAX;
        int   id = 0x7fffffff;
        for (int c = 0; c < 32; ++c) {
            int j = c * 256 + tid;
            const float4* c4 = (const float4*)(cb + (size_t)j * 16);
            float4 c0 = c4[0], c1 = c4[1], c2v = c4[2], c3 = c4[3];
            float dot = 0.f;
            dot = fmaf(a[0], c0.x, dot);   dot = fmaf(a[1], c0.y, dot);
            dot = fmaf(a[2], c0.z, dot);   dot = fmaf(a[3], c0.w, dot);
            dot = fmaf(a[4], c1.x, dot);   dot = fmaf(a[5], c1.y, dot);
            dot = fmaf(a[6], c1.z, dot);   dot = fmaf(a[7], c1.w, dot);
            dot = fmaf(a[8], c2v.x, dot);  dot = fmaf(a[9], c2v.y, dot);
            dot = fmaf(a[10], c2v.z, dot); dot = fmaf(a[11], c2v.w, dot);
            dot = fmaf(a[12], c3.x, dot);  dot = fmaf(a[13], c3.y, dot);
            dot = fmaf(a[14], c3.z, dot);  dot = fmaf(a[15], c3.w, dot);
            float e = fmaf(-2.f, dot, xx + c2g[j]);
            if (e < mn || (e == mn && j < id)) { mn = e; id = j; }
        }
        #pragma unroll
        for (int mask = 1; mask <= 32; mask <<= 1) {
            float pmn = __shfl_xor(mn, mask);
            int   pid = __shfl_xor(id, mask);
            if (pmn < mn || (pmn == mn && pid < id)) { mn = pmn; id = pid; }
        }
        if (lane == 0) { redE[wave] = mn; redI[wave] = id; }
        __syncthreads();
        if (tid == 0) {
            #pragma unroll
            for (int w = 1; w < 4; ++w) {
                float pe = redE[w]; int pi = redI[w];
                if (pe < mn || (pe == mn && pi < id)) { mn = pe; id = pi; }
            }
            out[blockIdx.x * 32 + ftk] = id;
        }
        __syncthreads();
    }
}

extern "C" void kernel_launch(void* const* d_in, const int* in_sizes, int n_in,
                              void* d_out, int out_size, void* d_ws, size_t ws_size,
                              hipStream_t stream) {
    const float* x   = (const float*)d_in[0];
    const float* P   = (const float*)d_in[1];
    const float* cbn = (const float*)d_in[2];

    float*    c2     = (float*)d_ws;                      // 8192 f
    ushort_t* cbpack = (ushort_t*)(c2 + NCODE);           // 8192*32 ushorts
    int* labels = (int*)d_out;

    pack_kernel<<<NCODE / 256, 256, 0, stream>>>(cbn, c2, cbpack);
    fused_kernel<<<TOKENS / 32, 256, 0, stream>>>(x, P, cbn, c2, cbpack, labels);
}